// Round 7
// baseline (64.837 us; speedup 1.0000x reference)
//
#include <hip/hip_runtime.h>

#define IMG 512
#define TW 64
#define TH 32
#define RROWS 42     // TH + 2*5
#define RST 80       // RAW stride (floats); RAW col j <-> gx = tx0-8+j
#define GST 64       // GH/HN/HX stride

__device__ __forceinline__ float nan0(float v){ return v==v ? v : 0.0f; }
__device__ __forceinline__ float min3f(float a,float b,float c){ return fminf(fminf(a,b),c); }
__device__ __forceinline__ float max3f(float a,float b,float c){ return fmaxf(fmaxf(a,b),c); }

__global__ __launch_bounds__(256)
void simplenet_fused(const float* __restrict__ X,
                     const float* __restrict__ w0, const float* __restrict__ b0,
                     const float* __restrict__ w1, const float* __restrict__ w2,
                     const float* __restrict__ w3, const float* __restrict__ w4,
                     const float* __restrict__ w5, const float* __restrict__ w6,
                     float* __restrict__ out)
{
    __shared__ float RAW[RROWS*RST];  // 13440 B raw tile, NaN = OOB sentinel
    __shared__ float GH [RROWS*GST];  // 10752 B gaussH (row r = RAW row r)
    __shared__ float HN [RROWS*GST];  // 10752 B h11 min
    __shared__ float HX [RROWS*GST];  // 10752 B h11 max   -> 45.7 KB total

    const int tid = threadIdx.x;
    const int xo = tid & 63, ty = tid >> 6, y0 = ty*8;   // 8 consecutive output rows/thread
    const int bx = blockIdx.x, by = blockIdx.y, bz = blockIdx.z;
    const int tx0 = bx*TW, ty0 = by*TH;
    const bool xe = (bx==0)||(bx==IMG/TW-1);
    const bool ye = (by==0)||(by==IMG/TH-1);
    const float* Xb = X + (size_t)bz*(IMG*IMG);

    const float W0c0=w0[0], W0c1=w0[1], B0=b0[0], B1=b0[1];
    const float W1c0=w1[0], W1c1=w1[1], W2c0=w2[0], W2c1=w2[1];
    const float W3c0=w3[0], W3c1=w3[1], W4c0=w4[0], W4c1=w4[1];
    const float W5c0=w5[0], W5c1=w5[1], W6c0=w6[0], W6c1=w6[1];

    // ---- P0: stage RAW (NaN sentinel for OOB) ----
    if (!xe) {
        for (int t=tid; t<RROWS*20; t+=256) {            // 840 float4 tasks
            const int r = t/20, c4 = t - r*20;
            const int gy = ty0 - 5 + r;
            float4 v;
            if (!ye || (unsigned)gy < IMG)
                v = *(const float4*)(Xb + gy*IMG + (tx0-8+4*c4));
            else { const float qn=__builtin_nanf(""); v = make_float4(qn,qn,qn,qn); }
            *(float4*)&RAW[r*RST + 4*c4] = v;
        }
    } else {
        for (int t=tid; t<RROWS*RST; t+=256) {
            const int r = t/RST, c = t - r*RST;
            const int gy = ty0-5+r, gx = tx0-8+c;
            RAW[r*RST+c] = ((unsigned)gy<IMG && (unsigned)gx<IMG)
                           ? Xb[gy*IMG+gx] : __builtin_nanf("");
        }
    }
    __syncthreads();

    const float G0=0.10628875f, G1=0.14032194f, G2=0.16577342f, G3=0.17523179f;

    // ---- P1: merged producer: gaussH + h11min + h11max per 4 cols ----
    // task (r,g): x[i] <-> RAW col 4g+i (i=0..19); output cols 4g+k <-> x[8+k]
    for (int t=tid; t<RROWS*16; t+=256) {                // 672 tasks
        const int r = t>>4, g = t&15;
        const float* Rb = &RAW[r*RST + 4*g];
        const float4 q0=*(const float4*)(Rb);
        const float4 q1=*(const float4*)(Rb+4);
        const float4 q2=*(const float4*)(Rb+8);
        const float4 q3=*(const float4*)(Rb+12);
        const float4 q4=*(const float4*)(Rb+16);
        const float x[20] = {q0.x,q0.y,q0.z,q0.w, q1.x,q1.y,q1.z,q1.w,
                             q2.x,q2.y,q2.z,q2.w, q3.x,q3.y,q3.z,q3.w,
                             q4.x,q4.y,q4.z,q4.w};
        // 3-wide running min/max, centers x[4..15]
        float mn[12], mx[12];
#pragma unroll
        for (int i=0;i<12;++i) {
            mn[i] = min3f(x[i+3],x[i+4],x[i+5]);
            mx[i] = max3f(x[i+3],x[i+4],x[i+5]);
        }
        // h11 (window +-5 around x[8+k]) = m3 at centers-4 offsets {k,k+3,k+6,k+8}
        float hn4[4], hx4[4];
#pragma unroll
        for (int k=0;k<4;++k) {
            hn4[k] = fminf(fminf(mn[k],mn[k+3]), fminf(mn[k+6],mn[k+8]));
            hx4[k] = fmaxf(fmaxf(mx[k],mx[k+3]), fmaxf(mx[k+6],mx[k+8]));
        }
        // gaussH: taps x[5..14] (zero-padded at x-edges; NaN rows propagate -> consumer nan0)
        float zz[10];
#pragma unroll
        for (int j=0;j<10;++j) zz[j] = xe ? nan0(x[5+j]) : x[5+j];
        float gh4[4];
#pragma unroll
        for (int k=0;k<4;++k)
            gh4[k] = G0*(zz[k]+zz[k+6]) + G1*(zz[k+1]+zz[k+5]) + G2*(zz[k+2]+zz[k+4]) + G3*zz[k+3];
        const int wbase = r*GST + 4*g;
        *(float4*)&GH[wbase] = make_float4(gh4[0],gh4[1],gh4[2],gh4[3]);
        *(float4*)&HN[wbase] = make_float4(hn4[0],hn4[1],hn4[2],hn4[3]);
        *(float4*)&HX[wbase] = make_float4(hx4[0],hx4[1],hx4[2],hx4[3]);
    }

    float a0[8], a1[8];

    // ---- P2: trio (identity + 3x3 cross + pool3) straight from RAW ----
    {
        const int xc = xo+8;
        float L[10], C[10], R[10];
#pragma unroll
        for (int i=0;i<10;++i) {
            const int rb = (y0+4+i)*RST + xc;
            L[i]=RAW[rb-1]; C[i]=RAW[rb]; R[i]=RAW[rb+1];
        }
        float hm[10], hxx[10];
#pragma unroll
        for (int i=0;i<10;++i) { hm[i]=min3f(L[i],C[i],R[i]); hxx[i]=max3f(L[i],C[i],R[i]); }
        // conv taps need zero-padding semantics
        float Lz[10], Rz[10];
#pragma unroll
        for (int i=0;i<10;++i) { Lz[i] = xe ? nan0(L[i]) : L[i];
                                 Rz[i] = xe ? nan0(R[i]) : R[i]; }
        const float Cz0 = ye ? nan0(C[0]) : C[0];
        const float Cz9 = ye ? nan0(C[9]) : C[9];
#pragma unroll
        for (int p=0;p<8;++p) {
            const float up = (p==0) ? Cz0 : C[p];
            const float dn = (p==7) ? Cz9 : C[p+2];
            const float cr = 0.25f*(up + dn + Lz[p+1] + Rz[p+1]);
            a0[p] = B0 + W0c0*C[p+1] + W1c0*cr;
            a1[p] = B1 + W0c1*C[p+1] + W1c1*cr;
            const float mnv = min3f(hm[p],hm[p+1],hm[p+2]);
            const float mxv = max3f(hxx[p],hxx[p+1],hxx[p+2]);
            a0[p] += W3c0*mnv + W5c0*mxv;
            a1[p] += W3c1*mnv + W5c1*mxv;
        }
    }
    __syncthreads();

    // ---- P3: gaussV (14 column reads -> 8 outputs) ----
    {
        float wv[14];
#pragma unroll
        for (int i=0;i<14;++i) wv[i] = GH[(y0+2+i)*GST + xo];
        if (ye) {
#pragma unroll
            for (int i=0;i<14;++i) wv[i] = nan0(wv[i]);
        }
#pragma unroll
        for (int p=0;p<8;++p) {
            const float s = G0*(wv[p]+wv[p+6]) + G1*(wv[p+1]+wv[p+5])
                          + G2*(wv[p+2]+wv[p+4]) + G3*wv[p+3];
            a0[p] += W2c0*s; a1[p] += W2c1*s;
        }
    }

    // ---- P4: v11 van Herk over 18 rows -> 8 outputs ----
    {
        float hn[18], hx[18];
#pragma unroll
        for (int i=0;i<18;++i) { hn[i]=HN[(y0+i)*GST+xo]; hx[i]=HX[(y0+i)*GST+xo]; }
        float sn[11], sx[11];
        sn[10]=hn[10]; sx[10]=hx[10];
#pragma unroll
        for (int i=9;i>=0;--i) { sn[i]=fminf(hn[i],sn[i+1]); sx[i]=fmaxf(hx[i],sx[i+1]); }
        a0[0] += W4c0*sn[0] + W6c0*sx[0];
        a1[0] += W4c1*sn[0] + W6c1*sx[0];
        float pn = hn[11], px = hx[11];
#pragma unroll
        for (int p=1;p<8;++p) {
            const float on = fminf(sn[p], pn);
            const float ox = fmaxf(sx[p], px);
            a0[p] += W4c0*on + W6c0*ox;
            a1[p] += W4c1*on + W6c1*ox;
            if (p<7) { pn = fminf(pn, hn[p+11]); px = fmaxf(px, hx[p+11]); }
        }
    }

    // ---- stores ----
    float* o0p = out + ((size_t)bz*2 + 0)*(IMG*IMG) + (size_t)(ty0+y0)*IMG + tx0 + xo;
    float* o1p = o0p + (IMG*IMG);
#pragma unroll
    for (int p=0;p<8;++p) {
        o0p[(size_t)p*IMG] = a0[p];
        o1p[(size_t)p*IMG] = a1[p];
    }
}

extern "C" void kernel_launch(void* const* d_in, const int* in_sizes, int n_in,
                              void* d_out, int out_size, void* d_ws, size_t ws_size,
                              hipStream_t stream) {
    const float* X  = (const float*)d_in[0];
    const float* w0 = (const float*)d_in[1];
    const float* b0 = (const float*)d_in[2];
    const float* w1 = (const float*)d_in[3];
    const float* w2 = (const float*)d_in[4];
    const float* w3 = (const float*)d_in[5];
    const float* w4 = (const float*)d_in[6];
    const float* w5 = (const float*)d_in[7];
    const float* w6 = (const float*)d_in[8];
    float* out = (float*)d_out;

    dim3 grid(IMG/TW, IMG/TH, 32);
    simplenet_fused<<<grid, 256, 0, stream>>>(X, w0, b0, w1, w2, w3, w4, w5, w6, out);
}

// Round 8
// 45.053 us; speedup vs baseline: 1.4391x; 1.4391x over previous
//
#include <hip/hip_runtime.h>

#define IMG 512
#define TW 64
#define TH 16
#define GST 64     // GH/HN/HX stride (floats)

__device__ __forceinline__ float nan0(float v){ return v==v ? v : 0.0f; }
__device__ __forceinline__ float min3f(float a,float b,float c){ return fminf(fminf(a,b),c); }
__device__ __forceinline__ float max3f(float a,float b,float c){ return fmaxf(fmaxf(a,b),c); }

__global__ __launch_bounds__(256)
void simplenet_fused(const float* __restrict__ X,
                     const float* __restrict__ w0, const float* __restrict__ b0,
                     const float* __restrict__ w1, const float* __restrict__ w2,
                     const float* __restrict__ w3, const float* __restrict__ w4,
                     const float* __restrict__ w5, const float* __restrict__ w6,
                     float* __restrict__ out)
{
    // Only h-pass results live in LDS (cross-thread exchange). Raw pixels are
    // read straight from global: the 8.3KB tile working set is L1-resident.
    __shared__ float GH[22*GST];   // 5632 B gaussH; row k = image row ty0-3+k
    __shared__ float HN[26*GST];   // 6656 B h11 min; row r = image row ty0-5+r
    __shared__ float HX[26*GST];   // 6656 B h11 max          -> 18944 B total

    const int tid = threadIdx.x;
    const int xo = tid & 63, ty = tid >> 6, y0 = ty*4;   // 4 consecutive rows/thread
    const int bx = blockIdx.x, by = blockIdx.y, bz = blockIdx.z;
    const int tx0 = bx*TW, ty0 = by*TH;
    const bool xe = (bx==0)||(bx==IMG/TW-1);
    const bool ye = (by==0)||(by==IMG/TH-1);
    const float* Xb = X + (size_t)bz*(IMG*IMG);
    const float qn = __builtin_nanf("");

    const float W0c0=w0[0], W0c1=w0[1], B0=b0[0], B1=b0[1];
    const float W1c0=w1[0], W1c1=w1[1], W2c0=w2[0], W2c1=w2[1];
    const float W3c0=w3[0], W3c1=w3[1], W4c0=w4[0], W4c1=w4[1];
    const float W5c0=w5[0], W5c1=w5[1], W6c0=w6[0], W6c1=w6[1];

    const float G0=0.10628875f, G1=0.14032194f, G2=0.16577342f, G3=0.17523179f;

    // ---- producers: 26 rows x 16 col-tasks; global->regs->LDS, no RAW buffer ----
    for (int t = tid; t < 26*16; t += 256) {
        const int r = t >> 4, g = t & 15;
        const int gy  = ty0 - 5 + r;
        const int gx0 = tx0 - 8 + 4*g;          // x[i] <-> global col gx0+i
        float x[20];
        const bool yv = !ye || ((unsigned)gy < IMG);
        if (yv) {
            if (!xe) {
#pragma unroll
                for (int j=0;j<5;++j) {
                    const float4 q = *(const float4*)(Xb + gy*IMG + gx0 + 4*j);
                    x[4*j]=q.x; x[4*j+1]=q.y; x[4*j+2]=q.z; x[4*j+3]=q.w;
                }
            } else {
                const float* row = Xb + gy*IMG;
#pragma unroll
                for (int j=0;j<5;++j) {
                    const int c0 = gx0 + 4*j;
                    if (c0 >= 0 && c0 + 3 < IMG) {
                        const float4 q = *(const float4*)(row + c0);
                        x[4*j]=q.x; x[4*j+1]=q.y; x[4*j+2]=q.z; x[4*j+3]=q.w;
                    } else {
#pragma unroll
                        for (int i=0;i<4;++i) {
                            const int gx = c0 + i;
                            const float v = row[min(max(gx,0),IMG-1)];
                            x[4*j+i] = ((unsigned)gx < IMG) ? v : qn;
                        }
                    }
                }
            }
        } else {
#pragma unroll
            for (int i=0;i<20;++i) x[i] = qn;
        }
        // 3-wide running min/max, center x[i+4]
        float mn[12], mx[12];
#pragma unroll
        for (int i=0;i<12;++i) {
            mn[i] = min3f(x[i+3],x[i+4],x[i+5]);
            mx[i] = max3f(x[i+3],x[i+4],x[i+5]);
        }
        float hn4[4], hx4[4];
#pragma unroll
        for (int k=0;k<4;++k) {                 // 11-window = m3 at offsets 0,3,6,8
            hn4[k] = fminf(fminf(mn[k],mn[k+3]), fminf(mn[k+6],mn[k+8]));
            hx4[k] = fmaxf(fmaxf(mx[k],mx[k+3]), fmaxf(mx[k+6],mx[k+8]));
        }
        *(float4*)&HN[r*GST+4*g] = make_float4(hn4[0],hn4[1],hn4[2],hn4[3]);
        *(float4*)&HX[r*GST+4*g] = make_float4(hx4[0],hx4[1],hx4[2],hx4[3]);
        if (r >= 2 && r < 24) {                 // gaussH only where the v-window needs it
            float zz[10];
#pragma unroll
            for (int j=0;j<10;++j) zz[j] = xe ? nan0(x[5+j]) : x[5+j];
            float gh4[4];
#pragma unroll
            for (int k=0;k<4;++k)
                gh4[k] = G0*(zz[k]+zz[k+6]) + G1*(zz[k+1]+zz[k+5]) + G2*(zz[k+2]+zz[k+4]) + G3*zz[k+3];
            *(float4*)&GH[(r-2)*GST+4*g] = make_float4(gh4[0],gh4[1],gh4[2],gh4[3]);
        }
    }

    float a0[4], a1[4];

    // ---- trio (identity + 3x3 cross + pool3) straight from global/L1 ----
    {
        const int gxc = tx0 + xo;
        float L[6], C[6], R[6];
        if (!xe && !ye) {
#pragma unroll
            for (int i=0;i<6;++i) {
                const float* row = Xb + (ty0+y0-1+i)*IMG + gxc;
                L[i]=row[-1]; C[i]=row[0]; R[i]=row[1];
            }
        } else {
#pragma unroll
            for (int i=0;i<6;++i) {
                const int gy = ty0+y0-1+i;
                const bool yv = (unsigned)gy < IMG;
                const float* row = Xb + (yv ? gy : 0)*IMG;
                float l = row[max(gxc-1,0)], c = row[gxc], r = row[min(gxc+1,IMG-1)];
                if (!yv) { l=qn; c=qn; r=qn; }
                if (gxc==0)     l=qn;
                if (gxc==IMG-1) r=qn;
                L[i]=l; C[i]=c; R[i]=r;
            }
        }
        float hm[6], hx6[6];
#pragma unroll
        for (int i=0;i<6;++i) { hm[i]=min3f(L[i],C[i],R[i]); hx6[i]=max3f(L[i],C[i],R[i]); }
        float Lz[6], Rz[6];
#pragma unroll
        for (int i=0;i<6;++i) { Lz[i] = xe ? nan0(L[i]) : L[i];
                                Rz[i] = xe ? nan0(R[i]) : R[i]; }
        const float Cz0 = ye ? nan0(C[0]) : C[0];
        const float Cz5 = ye ? nan0(C[5]) : C[5];
        const float up[4]={Cz0,C[1],C[2],C[3]};
        const float dn[4]={C[2],C[3],C[4],Cz5};
#pragma unroll
        for (int p=0;p<4;++p) {
            const float cr = 0.25f*(up[p] + dn[p] + Lz[p+1] + Rz[p+1]);
            a0[p] = B0 + W0c0*C[p+1] + W1c0*cr;
            a1[p] = B1 + W0c1*C[p+1] + W1c1*cr;
            const float mnv = min3f(hm[p],hm[p+1],hm[p+2]);
            const float mxv = max3f(hx6[p],hx6[p+1],hx6[p+2]);
            a0[p] += W3c0*mnv + W5c0*mxv;
            a1[p] += W3c1*mnv + W5c1*mxv;
        }
    }
    __syncthreads();

    // ---- gaussV (dense column b32 reads) ----
    {
        float wv[10];
#pragma unroll
        for (int i=0;i<10;++i) wv[i] = GH[(y0+i)*GST+xo];
        if (ye) {
#pragma unroll
            for (int i=0;i<10;++i) wv[i] = nan0(wv[i]);
        }
#pragma unroll
        for (int p=0;p<4;++p) {
            const float s = G0*(wv[p]+wv[p+6]) + G1*(wv[p+1]+wv[p+5])
                          + G2*(wv[p+2]+wv[p+4]) + G3*wv[p+3];
            a0[p] += W2c0*s; a1[p] += W2c1*s;
        }
    }

    // ---- v11 van Herk over 14 rows ----
    {
        float hn[14], hx[14];
#pragma unroll
        for (int i=0;i<14;++i) { hn[i]=HN[(y0+i)*GST+xo]; hx[i]=HX[(y0+i)*GST+xo]; }
        float an = hn[10], ax = hx[10];
#pragma unroll
        for (int i=9;i>=4;--i) { an=fminf(an,hn[i]); ax=fmaxf(ax,hx[i]); }
        const float Sn3=fminf(an,hn[3]),  Sx3=fmaxf(ax,hx[3]);
        const float Sn2=fminf(Sn3,hn[2]), Sx2=fmaxf(Sx3,hx[2]);
        const float Sn1=fminf(Sn2,hn[1]), Sx1=fmaxf(Sx2,hx[1]);
        const float Sn0=fminf(Sn1,hn[0]), Sx0=fmaxf(Sx1,hx[0]);
        const float pn1=hn[11],            px1=hx[11];
        const float pn2=fminf(pn1,hn[12]), px2=fmaxf(px1,hx[12]);
        const float pn3=fminf(pn2,hn[13]), px3=fmaxf(px2,hx[13]);
        const float on[4]={Sn0, fminf(Sn1,pn1), fminf(Sn2,pn2), fminf(Sn3,pn3)};
        const float ox[4]={Sx0, fmaxf(Sx1,px1), fmaxf(Sx2,px2), fmaxf(Sx3,px3)};
#pragma unroll
        for (int p=0;p<4;++p) {
            a0[p]+=W4c0*on[p]+W6c0*ox[p];
            a1[p]+=W4c1*on[p]+W6c1*ox[p];
        }
    }

    float* o0p = out + ((size_t)bz*2 + 0)*(IMG*IMG) + (size_t)(ty0+y0)*IMG + tx0 + xo;
    float* o1p = o0p + (IMG*IMG);
#pragma unroll
    for (int p=0;p<4;++p) {
        o0p[(size_t)p*IMG] = a0[p];
        o1p[(size_t)p*IMG] = a1[p];
    }
}

extern "C" void kernel_launch(void* const* d_in, const int* in_sizes, int n_in,
                              void* d_out, int out_size, void* d_ws, size_t ws_size,
                              hipStream_t stream) {
    const float* X  = (const float*)d_in[0];
    const float* w0 = (const float*)d_in[1];
    const float* b0 = (const float*)d_in[2];
    const float* w1 = (const float*)d_in[3];
    const float* w2 = (const float*)d_in[4];
    const float* w3 = (const float*)d_in[5];
    const float* w4 = (const float*)d_in[6];
    const float* w5 = (const float*)d_in[7];
    const float* w6 = (const float*)d_in[8];
    float* out = (float*)d_out;

    dim3 grid(IMG/TW, IMG/TH, 32);
    simplenet_fused<<<grid, 256, 0, stream>>>(X, w0, b0, w1, w2, w3, w4, w5, w6, out);
}